// Round 2
// baseline (220.263 us; speedup 1.0000x reference)
//
#include <hip/hip_runtime.h>
#include <math.h>

#define B  8
#define T  16
#define C  64
#define H  56
#define W  56
#define HW (H*W)          // 3136
#define HW4 (HW/4)        // 784
#define DS 8
#define DIN (DS*DS)       // 64
#define DOUT 32
#define BC (B*C)          // 512
#define GSL 2             // t-slices staged per group
#define NGRP (T/GSL)      // 8 groups

typedef float vfloat4 __attribute__((ext_vector_type(4)));

// ---------------------------------------------------------------------------
// Fully fused: pool + q/k + softmax + apply in ONE kernel.
// One block per n = b*C+c (512 blocks, 256 threads = 4 waves).
//
// R1 -> R2 change: LDS 77 KB -> ~35 KB to lift occupancy 2 -> 4 blocks/CU
// (8 -> 16 waves/CU, the VGPR<=128 tier limit). R1 counters showed
// FETCH ~= x read once (phase C re-read is cache-absorbed) but only
// 2.54 TB/s / 19.8% occupancy: latency-bound, not BW-bound.
//   - xs stages GSL=2 t-slices per group (24.5 KB, 8 groups).
//   - Wq/Wk no longer LDS-staged: identical 8 KB reads across all 512
//     blocks -> L1/L2 broadcast; phase B is tiny.
//   - __launch_bounds__(256,4): 4 waves/EU min -> VGPR cap 128.
//
// Phase A: stage 2 t-slices; 128 threads each reduce one 7x7 window
//          (2-way bank pattern = free).
// Phase B: q/k (64->32) from global weights, 16x16 logits, softmax ->
//          att_tr[s][t] (transposed, stride 16: phase C reads 4 coeffs per
//          broadcast ds_read_b128; softmax writes hit distinct banks).
// Phase C: out[t,col] = sum_s att[t][s] * x[s,col]. Each thread owns ALL
//          16 t's for its columns (acc[16] float4 = 64 VGPR) -> no
//          duplicated x loads. x re-read is L2/L3-warm (R1: FETCH ~= 99 MB
//          = x once). Non-temporal stores keep out from evicting x.
// ---------------------------------------------------------------------------
__global__ __launch_bounds__(256, 4) void fused_kernel(const float* __restrict__ x,
                                                       const float* __restrict__ Wq,
                                                       const float* __restrict__ bq,
                                                       const float* __restrict__ Wk,
                                                       const float* __restrict__ bk,
                                                       float* __restrict__ out) {
    __shared__ float xs[GSL * HW];        // 25088 B
    __shared__ float pooled_s[T * DIN];   // 4 KB
    __shared__ float qs[T * 33];          // padded stride 33 (2112 B)
    __shared__ float ks[T * 33];          // padded stride 33 (2112 B)
    __shared__ float att_s[T * T];        // logits (1 KB)
    __shared__ float att_tr[T * T];       // att transposed: [s][t] (1 KB)

    const int n = blockIdx.x;             // b*C + c
    const int tid = threadIdx.x;
    const int b = n >> 6;
    const int c = n & 63;

    const float4* x4 = (const float4*)x;
    float4* xs4 = (float4*)xs;

    // ---- Phase A: pool, GSL t-slices per group ----
    #pragma unroll 1
    for (int g = 0; g < NGRP; ++g) {
        for (int i = tid; i < GSL * HW4; i += 256) {
            const int ti = (i >= HW4) ? 1 : 0;      // GSL=2: compare, no div
            const int p  = i - ti * HW4;
            xs4[i] = x4[((size_t)(b * T + g * GSL + ti) * C + c) * HW4 + p];
        }
        __syncthreads();
        if (tid < GSL * 64) {
            const int ti  = tid >> 6;     // 0..1
            const int wi  = tid & 63;     // window index = ri*8+rj
            const int ri  = wi >> 3;
            const int rj  = wi & 7;
            float s = 0.f;
            const int base = ti * HW + (7 * ri) * W + 7 * rj;
            #pragma unroll
            for (int di = 0; di < 7; ++di) {
                #pragma unroll
                for (int dj = 0; dj < 7; ++dj) s += xs[base + di * W + dj];
            }
            pooled_s[(g * GSL + ti) * DIN + wi] = s * (1.0f / 49.0f);
        }
        __syncthreads();
    }

    // ---- Phase B: q,k (weights straight from global: L1/L2 broadcast) ----
    for (int e = tid; e < T * DOUT; e += 256) {
        const int t = e >> 5;
        const int d = e & 31;
        float sq = bq[d];
        float sk = bk[d];
        #pragma unroll 8
        for (int kk = 0; kk < DIN; ++kk) {
            const float f = pooled_s[t * DIN + kk];
            sq = fmaf(f, Wq[kk * DOUT + d], sq);
            sk = fmaf(f, Wk[kk * DOUT + d], sk);
        }
        qs[t * 33 + d] = sq;
        ks[t * 33 + d] = sk;
    }
    __syncthreads();

    // logits (one per thread)
    {
        const int tt = tid >> 4;
        const int ss = tid & 15;
        float s = 0.f;
        #pragma unroll
        for (int d = 0; d < DOUT; ++d) s = fmaf(qs[tt * 33 + d], ks[ss * 33 + d], s);
        att_s[tid] = s * 0.25f;           // 1/sqrt(16)
    }
    __syncthreads();

    // softmax rows (16 threads), write TRANSPOSED for phase C b128 reads
    if (tid < T) {
        const int r = tid;
        float m = -INFINITY;
        #pragma unroll
        for (int s = 0; s < T; ++s) m = fmaxf(m, att_s[r * T + s]);
        float e[T];
        float sum = 0.f;
        #pragma unroll
        for (int s = 0; s < T; ++s) { e[s] = __expf(att_s[r * T + s] - m); sum += e[s]; }
        const float inv = 1.0f / sum;
        #pragma unroll
        for (int s = 0; s < T; ++s) att_tr[s * T + r] = e[s] * inv;  // banks r+16(s&1)
    }
    __syncthreads();

    // ---- Phase C: apply. out[t,col] = sum_s att_tr[s][t] * x[s,col] ----
    const float4* att4 = (const float4*)att_tr;   // att4[s*4+q] = att[t=4q..4q+3][s]
    float4* o4 = (float4*)out;
    const size_t xbase = ((size_t)(b * T) * C + c) * HW4;
    const size_t tstride = (size_t)C * HW4;       // float4 stride between t-slices

    #pragma unroll 1
    for (int i = tid; i < HW4; i += 256) {
        float4 acc[16];
        #pragma unroll
        for (int t = 0; t < 16; ++t) acc[t] = make_float4(0.f, 0.f, 0.f, 0.f);

        #pragma unroll 4
        for (int s = 0; s < T; ++s) {
            const float4 xv = x4[xbase + (size_t)s * tstride + i];
            #pragma unroll
            for (int q = 0; q < 4; ++q) {
                const float4 a = att4[s * 4 + q];   // broadcast ds_read_b128
                acc[q*4+0].x = fmaf(a.x, xv.x, acc[q*4+0].x);
                acc[q*4+0].y = fmaf(a.x, xv.y, acc[q*4+0].y);
                acc[q*4+0].z = fmaf(a.x, xv.z, acc[q*4+0].z);
                acc[q*4+0].w = fmaf(a.x, xv.w, acc[q*4+0].w);
                acc[q*4+1].x = fmaf(a.y, xv.x, acc[q*4+1].x);
                acc[q*4+1].y = fmaf(a.y, xv.y, acc[q*4+1].y);
                acc[q*4+1].z = fmaf(a.y, xv.z, acc[q*4+1].z);
                acc[q*4+1].w = fmaf(a.y, xv.w, acc[q*4+1].w);
                acc[q*4+2].x = fmaf(a.z, xv.x, acc[q*4+2].x);
                acc[q*4+2].y = fmaf(a.z, xv.y, acc[q*4+2].y);
                acc[q*4+2].z = fmaf(a.z, xv.z, acc[q*4+2].z);
                acc[q*4+2].w = fmaf(a.z, xv.w, acc[q*4+2].w);
                acc[q*4+3].x = fmaf(a.w, xv.x, acc[q*4+3].x);
                acc[q*4+3].y = fmaf(a.w, xv.y, acc[q*4+3].y);
                acc[q*4+3].z = fmaf(a.w, xv.z, acc[q*4+3].z);
                acc[q*4+3].w = fmaf(a.w, xv.w, acc[q*4+3].w);
            }
        }

        #pragma unroll
        for (int t = 0; t < 16; ++t) {
            vfloat4* dst = (vfloat4*)&o4[xbase + (size_t)t * tstride + i];
            vfloat4 v; v.x = acc[t].x; v.y = acc[t].y; v.z = acc[t].z; v.w = acc[t].w;
            __builtin_nontemporal_store(v, dst);
        }
    }
}

extern "C" void kernel_launch(void* const* d_in, const int* in_sizes, int n_in,
                              void* d_out, int out_size, void* d_ws, size_t ws_size,
                              hipStream_t stream) {
    const float* x  = (const float*)d_in[0];
    const float* Wq = (const float*)d_in[1];
    const float* bq = (const float*)d_in[2];
    const float* Wk = (const float*)d_in[3];
    const float* bk = (const float*)d_in[4];
    float* out = (float*)d_out;

    fused_kernel<<<dim3(BC), dim3(256), 0, stream>>>(x, Wq, bq, Wk, bk, out);
}

// Round 4
// 211.713 us; speedup vs baseline: 1.0404x; 1.0404x over previous
//
#include <hip/hip_runtime.h>
#include <math.h>

#define B  8
#define T  16
#define C  64
#define H  56
#define W  56
#define HW (H*W)          // 3136
#define HW4 (HW/4)        // 784
#define DS 8
#define DIN (DS*DS)       // 64
#define DOUT 32
#define BC (B*C)          // 512

typedef float vfloat4 __attribute__((ext_vector_type(4)));

// ---------------------------------------------------------------------------
// R2 -> R3/R4: the fused kernel was GRID-capped at 2 blocks/CU (512 blocks on
// 256 CUs) -> 19.7% occupancy, 2.3-2.5 TB/s, latency-bound. Split into 3
// stream-ordered kernels, each with a machine-sized grid. (R3 submission
// never ran — broker timeout; resubmitted unchanged.)
// ---------------------------------------------------------------------------

// K1: pool. Block per (n,t): 8192 blocks x 256 thr, 13.5 KB LDS -> 8
// blocks/CU (wave-capped => ~full occupancy). Stage one t-slice (12.25 KB),
// all 4 waves cooperate: wave q handles rows {2q,2q+1} (q<3) or {6} (q=3)
// of every 7x7 window -> wave-uniform, no divergence; xs reads are exactly
// 2-way bank-aliased (free). Partials combined via 1 KB LDS.
// pooled output goes into the head of `out` (scratch until K3 overwrites).
__global__ __launch_bounds__(256) void pool_kernel(const float* __restrict__ x,
                                                   float* __restrict__ pooled_g) {
    __shared__ float xs[HW];      // 12544 B
    __shared__ float part[256];   // 1 KB
    const int n = blockIdx.x;     // b*C + c
    const int t = blockIdx.y;
    const int tid = threadIdx.x;
    const int b = n >> 6;
    const int c = n & 63;

    const float4* x4 = (const float4*)x;
    float4* xs4 = (float4*)xs;
    const size_t base = ((size_t)(b * T + t) * C + c) * HW4;

    for (int i = tid; i < HW4; i += 256) xs4[i] = x4[base + i];
    __syncthreads();

    {
        const int wi = tid & 63;      // window = ri*8+rj
        const int q  = tid >> 6;      // wave index -> row group (uniform)
        const int ri = wi >> 3;
        const int rj = wi & 7;
        const int r0 = 2 * q;
        const int nrows = (q < 3) ? 2 : 1;
        float s = 0.f;
        for (int dr = 0; dr < nrows; ++dr) {
            const int row = 7 * ri + r0 + dr;
            const int col0 = 7 * rj;
            #pragma unroll
            for (int dj = 0; dj < 7; ++dj) s += xs[row * W + col0 + dj];
        }
        part[q * 64 + wi] = s;
    }
    __syncthreads();

    if (tid < 64) {
        const float v = part[tid] + part[tid + 64] + part[tid + 128] + part[tid + 192];
        pooled_g[((size_t)n * T + t) * DIN + tid] = v * (1.0f / 49.0f);
    }
}

// K2: q/k + logits + softmax per n. 512 blocks x 256 thr (small glue kernel,
// inputs L2/L3-hot: pooled 2 MB + weights 16 KB). att written row-major.
__global__ __launch_bounds__(256) void att_kernel(const float* __restrict__ pooled_g,
                                                  const float* __restrict__ Wq,
                                                  const float* __restrict__ bq,
                                                  const float* __restrict__ Wk,
                                                  const float* __restrict__ bk,
                                                  float* __restrict__ att_g) {
    __shared__ float pooled_s[T * DIN];   // 4 KB
    __shared__ float qs[T * 33];
    __shared__ float ks[T * 33];
    __shared__ float att_s[T * T];

    const int n = blockIdx.x;
    const int tid = threadIdx.x;

    for (int e = tid; e < T * DIN; e += 256) pooled_s[e] = pooled_g[(size_t)n * (T * DIN) + e];
    __syncthreads();

    for (int e = tid; e < T * DOUT; e += 256) {
        const int t = e >> 5;
        const int d = e & 31;
        float sq = bq[d];
        float sk = bk[d];
        #pragma unroll 8
        for (int kk = 0; kk < DIN; ++kk) {
            const float f = pooled_s[t * DIN + kk];
            sq = fmaf(f, Wq[kk * DOUT + d], sq);
            sk = fmaf(f, Wk[kk * DOUT + d], sk);
        }
        qs[t * 33 + d] = sq;
        ks[t * 33 + d] = sk;
    }
    __syncthreads();

    {
        const int tt = tid >> 4;
        const int ss = tid & 15;
        float s = 0.f;
        #pragma unroll
        for (int d = 0; d < DOUT; ++d) s = fmaf(qs[tt * 33 + d], ks[ss * 33 + d], s);
        att_s[tid] = s * 0.25f;           // 1/sqrt(16)
    }
    __syncthreads();

    if (tid < T) {
        const int r = tid;
        float m = -INFINITY;
        #pragma unroll
        for (int s = 0; s < T; ++s) m = fmaxf(m, att_s[r * T + s]);
        float e[T];
        float sum = 0.f;
        #pragma unroll
        for (int s = 0; s < T; ++s) { e[s] = __expf(att_s[r * T + s] - m); sum += e[s]; }
        const float inv = 1.0f / sum;
        #pragma unroll
        for (int s = 0; s < T; ++s) att_g[(size_t)n * (T * T) + r * T + s] = e[s] * inv;
    }
}

// K3: apply. out[t,col] = sum_s att[t][s] * x[s,col]. Proven R0 structure
// (85 VGPR, no spill): 128 thr, wave 0 -> t 0..7, wave 1 -> t 8..15,
// acc[8] float4, s-loop unroll 8, NT stores. Grid widened (512,4)->(512,7):
// 112 float4-cols per block, 3584 blocks -> ~16 waves/CU. x reads L3-warm
// (K1 just streamed x; 102 MB < 256 MB LLC).
__global__ __launch_bounds__(128) void apply_kernel(const float* __restrict__ x,
                                                    const float* __restrict__ att_g,
                                                    float* __restrict__ out) {
    __shared__ float att_s[T * T];
    const int n = blockIdx.x;             // [0,512)
    const int chunk = blockIdx.y;         // [0,7)
    const int tid = threadIdx.x;
    const int lane = tid & 63;
    const int wave = tid >> 6;            // 0..1 -> t-half
    const int b = n >> 6;
    const int c = n & 63;

    for (int e = tid; e < T * T; e += 128) att_s[e] = att_g[(size_t)n * (T * T) + e];
    __syncthreads();

    const float4* x4 = (const float4*)x;
    float4* o4 = (float4*)out;

    #pragma unroll 1
    for (int i = lane; i < 112; i += 64) {
        const int p4 = chunk * 112 + i;
        float4 acc[8];
        #pragma unroll
        for (int t = 0; t < 8; ++t) acc[t] = make_float4(0.f, 0.f, 0.f, 0.f);

        #pragma unroll 8
        for (int s = 0; s < T; ++s) {
            const float4 xv = x4[((size_t)(b * T + s) * C + c) * HW4 + p4];
            #pragma unroll
            for (int t = 0; t < 8; ++t) {
                const float a = att_s[(wave * 8 + t) * T + s];  // wave-uniform broadcast
                acc[t].x = fmaf(a, xv.x, acc[t].x);
                acc[t].y = fmaf(a, xv.y, acc[t].y);
                acc[t].z = fmaf(a, xv.z, acc[t].z);
                acc[t].w = fmaf(a, xv.w, acc[t].w);
            }
        }

        #pragma unroll
        for (int t = 0; t < 8; ++t) {
            vfloat4* dst = (vfloat4*)&o4[((size_t)(b * T + wave * 8 + t) * C + c) * HW4 + p4];
            vfloat4 v; v.x = acc[t].x; v.y = acc[t].y; v.z = acc[t].z; v.w = acc[t].w;
            __builtin_nontemporal_store(v, dst);
        }
    }
}

extern "C" void kernel_launch(void* const* d_in, const int* in_sizes, int n_in,
                              void* d_out, int out_size, void* d_ws, size_t ws_size,
                              hipStream_t stream) {
    const float* x  = (const float*)d_in[0];
    const float* Wq = (const float*)d_in[1];
    const float* bq = (const float*)d_in[2];
    const float* Wk = (const float*)d_in[3];
    const float* bk = (const float*)d_in[4];
    float* out = (float*)d_out;

    // pooled (2 MB) lives in the head of `out` — scratch until K3 overwrites
    // it (stream-ordered: K2 consumes it before K3 launches any writes).
    float* pooled_g = out;
    float* att_g = (float*)d_ws;          // 512*256 floats = 512 KB

    pool_kernel<<<dim3(BC, T), dim3(256), 0, stream>>>(x, pooled_g);
    att_kernel<<<dim3(BC), dim3(256), 0, stream>>>(pooled_g, Wq, bq, Wk, bk, att_g);
    apply_kernel<<<dim3(BC, 7), dim3(128), 0, stream>>>(x, att_g, out);
}

// Round 6
// 211.558 us; speedup vs baseline: 1.0411x; 1.0007x over previous
//
#include <hip/hip_runtime.h>
#include <math.h>

#define B  8
#define T  16
#define C  64
#define H  56
#define W  56
#define HW (H*W)          // 3136
#define HW4 (HW/4)        // 784
#define DS 8
#define DIN (DS*DS)       // 64
#define DOUT 32
#define BC (B*C)          // 512

typedef float vfloat4 __attribute__((ext_vector_type(4)));

// ---------------------------------------------------------------------------
// R4 -> R5/R6: R4 counters showed the harness fills (~129 us fixed) dominate
// the bench; our 3 kernels total ~83 us. K3 carried the old wave-pair
// structure where both waves load identical x float4s (2x L1/L2 requests)
// and read att as 128 scalar ds_read_b32 per column. New K3: each thread
// owns ALL 16 t's (acc[16] float4 = 64 VGPR, no duplicated loads), att
// transposed in LDS so per-s coefficients are 4 broadcast ds_read_b128.
// K1/K2 unchanged (single-variable attribution: bench delta == K3 delta).
// (R5 submission never ran — broker timeout; resubmitted unchanged.)
// ---------------------------------------------------------------------------

// K1: pool. Block per (n,t): 8192 blocks x 256 thr, 13.5 KB LDS -> 8
// blocks/CU. Stage one t-slice (12.25 KB); wave q handles rows {2q,2q+1}
// (q<3) or {6} (q=3) of every 7x7 window -> wave-uniform; xs reads are
// 2-way bank-aliased (free). Partials combined via 1 KB LDS.
__global__ __launch_bounds__(256) void pool_kernel(const float* __restrict__ x,
                                                   float* __restrict__ pooled_g) {
    __shared__ float xs[HW];      // 12544 B
    __shared__ float part[256];   // 1 KB
    const int n = blockIdx.x;     // b*C + c
    const int t = blockIdx.y;
    const int tid = threadIdx.x;
    const int b = n >> 6;
    const int c = n & 63;

    const float4* x4 = (const float4*)x;
    float4* xs4 = (float4*)xs;
    const size_t base = ((size_t)(b * T + t) * C + c) * HW4;

    for (int i = tid; i < HW4; i += 256) xs4[i] = x4[base + i];
    __syncthreads();

    {
        const int wi = tid & 63;      // window = ri*8+rj
        const int q  = tid >> 6;      // wave index -> row group (uniform)
        const int ri = wi >> 3;
        const int rj = wi & 7;
        const int r0 = 2 * q;
        const int nrows = (q < 3) ? 2 : 1;
        float s = 0.f;
        for (int dr = 0; dr < nrows; ++dr) {
            const int row = 7 * ri + r0 + dr;
            const int col0 = 7 * rj;
            #pragma unroll
            for (int dj = 0; dj < 7; ++dj) s += xs[row * W + col0 + dj];
        }
        part[q * 64 + wi] = s;
    }
    __syncthreads();

    if (tid < 64) {
        const float v = part[tid] + part[tid + 64] + part[tid + 128] + part[tid + 192];
        pooled_g[((size_t)n * T + t) * DIN + tid] = v * (1.0f / 49.0f);
    }
}

// K2: q/k + logits + softmax per n. 512 blocks x 256 thr (glue; inputs
// L2/L3-hot: pooled 2 MB + weights 16 KB). att written row-major [t][s].
__global__ __launch_bounds__(256) void att_kernel(const float* __restrict__ pooled_g,
                                                  const float* __restrict__ Wq,
                                                  const float* __restrict__ bq,
                                                  const float* __restrict__ Wk,
                                                  const float* __restrict__ bk,
                                                  float* __restrict__ att_g) {
    __shared__ float pooled_s[T * DIN];   // 4 KB
    __shared__ float qs[T * 33];
    __shared__ float ks[T * 33];
    __shared__ float att_s[T * T];

    const int n = blockIdx.x;
    const int tid = threadIdx.x;

    for (int e = tid; e < T * DIN; e += 256) pooled_s[e] = pooled_g[(size_t)n * (T * DIN) + e];
    __syncthreads();

    for (int e = tid; e < T * DOUT; e += 256) {
        const int t = e >> 5;
        const int d = e & 31;
        float sq = bq[d];
        float sk = bk[d];
        #pragma unroll 8
        for (int kk = 0; kk < DIN; ++kk) {
            const float f = pooled_s[t * DIN + kk];
            sq = fmaf(f, Wq[kk * DOUT + d], sq);
            sk = fmaf(f, Wk[kk * DOUT + d], sk);
        }
        qs[t * 33 + d] = sq;
        ks[t * 33 + d] = sk;
    }
    __syncthreads();

    {
        const int tt = tid >> 4;
        const int ss = tid & 15;
        float s = 0.f;
        #pragma unroll
        for (int d = 0; d < DOUT; ++d) s = fmaf(qs[tt * 33 + d], ks[ss * 33 + d], s);
        att_s[tid] = s * 0.25f;           // 1/sqrt(16)
    }
    __syncthreads();

    if (tid < T) {
        const int r = tid;
        float m = -INFINITY;
        #pragma unroll
        for (int s = 0; s < T; ++s) m = fmaxf(m, att_s[r * T + s]);
        float e[T];
        float sum = 0.f;
        #pragma unroll
        for (int s = 0; s < T; ++s) { e[s] = __expf(att_s[r * T + s] - m); sum += e[s]; }
        const float inv = 1.0f / sum;
        #pragma unroll
        for (int s = 0; s < T; ++s) att_g[(size_t)n * (T * T) + r * T + s] = e[s] * inv;
    }
}

// K3: apply. out[t,col] = sum_s att[t][s] * x[s,col].
// Grid (512,7) x 128 thr; lanes 0..111 each own ONE float4 column and ALL
// 16 t's: acc[16] float4 = 64 VGPR, NO duplicated x loads (old version
// loaded every xv twice across the wave pair). att transposed in LDS
// ([s][t], so att4[s*4+q] is a broadcast ds_read_b128 giving t=4q..4q+3).
// s-loop unroll 4 bounds in-flight loads (~110 VGPR, no spill; no forced
// min-waves — R2 lesson). x reads are L3-warm (K1 just streamed x, 102 MB
// < 256 MB LLC). Non-temporal stores keep out from evicting x.
__global__ __launch_bounds__(128) void apply_kernel(const float* __restrict__ x,
                                                    const float* __restrict__ att_g,
                                                    float* __restrict__ out) {
    __shared__ float att_tr[T * T];       // [s][t]
    const int n = blockIdx.x;             // [0,512)
    const int chunk = blockIdx.y;         // [0,7)
    const int tid = threadIdx.x;
    const int b = n >> 6;
    const int c = n & 63;

    #pragma unroll
    for (int e = tid; e < T * T; e += 128) {
        const int t = e >> 4;
        const int s = e & 15;
        att_tr[s * T + t] = att_g[(size_t)n * (T * T) + e];   // one-time transpose
    }
    __syncthreads();

    if (tid < 112) {
        const float4* x4 = (const float4*)x;
        float4* o4 = (float4*)out;
        const float4* att4 = (const float4*)att_tr;   // att4[s*4+q] = att[4q..4q+3][s]
        const size_t xbase = ((size_t)(b * T) * C + c) * HW4;
        const size_t tstride = (size_t)C * HW4;
        const int p4 = chunk * 112 + tid;

        float4 acc[16];
        #pragma unroll
        for (int t = 0; t < 16; ++t) acc[t] = make_float4(0.f, 0.f, 0.f, 0.f);

        #pragma unroll 4
        for (int s = 0; s < T; ++s) {
            const float4 xv = x4[xbase + (size_t)s * tstride + p4];
            #pragma unroll
            for (int q = 0; q < 4; ++q) {
                const float4 a = att4[s * 4 + q];     // broadcast ds_read_b128
                acc[q*4+0].x = fmaf(a.x, xv.x, acc[q*4+0].x);
                acc[q*4+0].y = fmaf(a.x, xv.y, acc[q*4+0].y);
                acc[q*4+0].z = fmaf(a.x, xv.z, acc[q*4+0].z);
                acc[q*4+0].w = fmaf(a.x, xv.w, acc[q*4+0].w);
                acc[q*4+1].x = fmaf(a.y, xv.x, acc[q*4+1].x);
                acc[q*4+1].y = fmaf(a.y, xv.y, acc[q*4+1].y);
                acc[q*4+1].z = fmaf(a.y, xv.z, acc[q*4+1].z);
                acc[q*4+1].w = fmaf(a.y, xv.w, acc[q*4+1].w);
                acc[q*4+2].x = fmaf(a.z, xv.x, acc[q*4+2].x);
                acc[q*4+2].y = fmaf(a.z, xv.y, acc[q*4+2].y);
                acc[q*4+2].z = fmaf(a.z, xv.z, acc[q*4+2].z);
                acc[q*4+2].w = fmaf(a.z, xv.w, acc[q*4+2].w);
                acc[q*4+3].x = fmaf(a.w, xv.x, acc[q*4+3].x);
                acc[q*4+3].y = fmaf(a.w, xv.y, acc[q*4+3].y);
                acc[q*4+3].z = fmaf(a.w, xv.z, acc[q*4+3].z);
                acc[q*4+3].w = fmaf(a.w, xv.w, acc[q*4+3].w);
            }
        }

        #pragma unroll
        for (int t = 0; t < 16; ++t) {
            vfloat4* dst = (vfloat4*)&o4[xbase + (size_t)t * tstride + p4];
            vfloat4 v; v.x = acc[t].x; v.y = acc[t].y; v.z = acc[t].z; v.w = acc[t].w;
            __builtin_nontemporal_store(v, dst);
        }
    }
}

extern "C" void kernel_launch(void* const* d_in, const int* in_sizes, int n_in,
                              void* d_out, int out_size, void* d_ws, size_t ws_size,
                              hipStream_t stream) {
    const float* x  = (const float*)d_in[0];
    const float* Wq = (const float*)d_in[1];
    const float* bq = (const float*)d_in[2];
    const float* Wk = (const float*)d_in[3];
    const float* bk = (const float*)d_in[4];
    float* out = (float*)d_out;

    // pooled (2 MB) lives in the head of `out` — scratch until K3 overwrites
    // it (stream-ordered: K2 consumes it before K3 launches any writes).
    float* pooled_g = out;
    float* att_g = (float*)d_ws;          // 512*256 floats = 512 KB

    pool_kernel<<<dim3(BC, T), dim3(256), 0, stream>>>(x, pooled_g);
    att_kernel<<<dim3(BC), dim3(256), 0, stream>>>(pooled_g, Wq, bq, Wk, bk, att_g);
    apply_kernel<<<dim3(BC, 7), dim3(128), 0, stream>>>(x, att_g, out);
}